// Round 6
// baseline (48.796 us; speedup 1.0000x reference)
//
#include <hip/hip_runtime.h>

#define HH 256
#define WW 256
#define NB 4
#define NC 4
#define NPIX (HH*WW)            // 65536
#define NIMG (NB*NC)            // 16
#define TOTAL (NB*NC*HH*WW)     // 1048576
#define INF_G (1<<30)

__device__ __forceinline__ float wave_reduce(float v) {
    #pragma unroll
    for (int off = 32; off > 0; off >>= 1) v += __shfl_down(v, off);
    return v;
}

// distance from x to nearest set bit in a 256-bit mask (4 u64 words); INT_MAX if none
__device__ __forceinline__ int nearest_dist(const unsigned long long* m, int x) {
    int best = 0x7fffffff;
    #pragma unroll
    for (int w = 0; w < 4; ++w) {
        unsigned long long mm = m[w];
        if (!mm) continue;
        int rel = x - (w << 6);
        // left side: highest set bit at position <= rel
        unsigned long long lmask = (rel >= 63) ? ~0ull
                                 : ((rel < 0) ? 0ull : ((2ull << (rel & 63)) - 1ull));
        unsigned long long lm = mm & lmask;
        if (lm) best = min(best, rel - (63 - __clzll(lm)));
        // right side: lowest set bit at position >= rel
        unsigned long long rmask = (rel <= 0) ? ~0ull
                                 : ((rel > 63) ? 0ull : (~0ull << (rel & 63)));
        unsigned long long rm = mm & rmask;
        if (rm) best = min(best, (__ffsll((long long)rm) - 1) - rel);
    }
    return best;
}

// Fused softmax + row-DT. block = (b, y); thread = x. (verified: absmax 0)
// Writes TRANSPOSED so the column pass reads coalesced:
//   dbuf_t[img][x][y] = ushort4{d(~fgP), d(fgP), d(~fgT), d(fgT)}  (0xFFFF = row empty)
//   peT  [img][x][y] = (p - t)^2
// Also zeroes out[0] (timed replays don't re-poison; kernel boundary publishes it).
__global__ void fused_rows(const float* __restrict__ pred, const int* __restrict__ target,
                           ushort4* __restrict__ dbuf_t, float* __restrict__ peT,
                           float* __restrict__ out) {
    int blk = blockIdx.x;           // b*256 + y
    int b = blk >> 8, y = blk & 255;
    int x = threadIdx.x;

    if (blk == 0 && x == 0) out[0] = 0.0f;

    const float* base = pred + (((size_t)b * NC) * HH + y) * WW + x;
    float v0 = base[0 * (size_t)NPIX];
    float v1 = base[1 * (size_t)NPIX];
    float v2 = base[2 * (size_t)NPIX];
    float v3 = base[3 * (size_t)NPIX];
    float m = fmaxf(fmaxf(v0, v1), fmaxf(v2, v3));
    float e0 = expf(v0 - m), e1 = expf(v1 - m), e2 = expf(v2 - m), e3 = expf(v3 - m);
    float inv = 1.0f / (e0 + e1 + e2 + e3);
    float p[4] = { e0 * inv, e1 * inv, e2 * inv, e3 * inv };

    int tc = target[((size_t)b * HH + y) * WW + x];

    __shared__ unsigned long long mP[4][4], mT[4][4];   // [class][word]
    int lane = x & 63, wave = x >> 6;
    #pragma unroll
    for (int c = 0; c < 4; ++c) {
        unsigned long long bp = __ballot(p[c] > 0.5f);
        unsigned long long bt = __ballot(tc == c);
        if (lane == 0) { mP[c][wave] = bp; mT[c][wave] = bt; }
    }
    __syncthreads();

    #pragma unroll
    for (int c = 0; c < 4; ++c) {
        unsigned long long wp[4], wt[4], np[4], nt[4];
        #pragma unroll
        for (int w = 0; w < 4; ++w) {
            wp[w] = mP[c][w]; wt[w] = mT[c][w];
            np[w] = ~wp[w];   nt[w] = ~wt[w];
        }
        int d0 = nearest_dist(np, x);   // ~fgP
        int d1 = nearest_dist(wp, x);   // fgP
        int d2 = nearest_dist(nt, x);   // ~fgT
        int d3 = nearest_dist(wt, x);   // fgT

        ushort4 outv;
        outv.x = (d0 > 255) ? 0xFFFF : (unsigned short)d0;
        outv.y = (d1 > 255) ? 0xFFFF : (unsigned short)d1;
        outv.z = (d2 > 255) ? 0xFFFF : (unsigned short)d2;
        outv.w = (d3 > 255) ? 0xFFFF : (unsigned short)d3;

        size_t ti = (((size_t)(b * NC + c)) * WW + x) * HH + y;   // transposed
        dbuf_t[ti] = outv;

        float t = (tc == c) ? 1.0f : 0.0f;
        float d = p[c] - t;
        peT[ti] = d * d;
    }
}

// Column pass + loss + final accumulation. block = (img, 4 columns), thread = y.
// best(y) = min_j d_row(j)^2 + (y-j)^2, searched outward with early exit.
// any(fg) over image == exists row with d != 0xFFFF (row-empty marker is x-independent).
// Block partial is added to out[0] with one hw fp32 LLC atomic per block.
__global__ void dt_cols_loss(const ushort4* __restrict__ dbuf_t, const float* __restrict__ peT,
                             float* __restrict__ out) {
    int blk = blockIdx.x;
    int img = blk >> 6;
    int xbase = (blk & 63) * 4;
    int y = threadIdx.x;
    int lane = y & 63, wv = y >> 6;

    __shared__ int g[4][HH];
    __shared__ int sF[8];
    __shared__ float sred[4];

    ushort4 dvk[4];
    float pek[4];
    #pragma unroll
    for (int k = 0; k < 4; ++k) {
        size_t ti = (((size_t)img) * WW + (xbase + k)) * HH + y;
        dvk[k] = dbuf_t[ti];
        pek[k] = peT[ti];
    }

    // image-wide "any fg" flags
    unsigned long long bP = __ballot(dvk[0].y != 0xFFFF);
    unsigned long long bT = __ballot(dvk[0].w != 0xFFFF);
    if (lane == 0) { sF[wv] = (bP != 0ull); sF[4 + wv] = (bT != 0ull); }

    float acc = 0.0f;
    #pragma unroll
    for (int k = 0; k < 4; ++k) {
        __syncthreads();    // protect g overwrite (k=0 also publishes sF)
        g[0][y] = (dvk[k].x == 0xFFFF) ? INF_G : (int)dvk[k].x * (int)dvk[k].x;
        g[1][y] = (dvk[k].y == 0xFFFF) ? INF_G : (int)dvk[k].y * (int)dvk[k].y;
        g[2][y] = (dvk[k].z == 0xFFFF) ? INF_G : (int)dvk[k].z * (int)dvk[k].z;
        g[3][y] = (dvk[k].w == 0xFFFF) ? INF_G : (int)dvk[k].w * (int)dvk[k].w;
        __syncthreads();

        float dt[4];
        #pragma unroll
        for (int v = 0; v < 4; ++v) {
            int best = g[v][y];
            for (int s = 1; s < HH; ++s) {
                int ss = s * s;
                if (ss >= best) break;
                int jm = y - s;
                if (jm >= 0) best = min(best, g[v][jm] + ss);
                int jp = y + s;
                if (jp < HH) best = min(best, g[v][jp] + ss);
            }
            dt[v] = (best >= INF_G) ? sqrtf(1.0e9f) : sqrtf((float)best);
        }

        int hs1 = sF[0] | sF[1] | sF[2] | sF[3];   // any(fgP)
        int hs3 = sF[4] | sF[5] | sF[6] | sF[7];   // any(fgT)
        float pd = hs1 ? (dt[0] + dt[1]) : 0.0f;
        float td = hs3 ? (dt[2] + dt[3]) : 0.0f;
        acc += pek[k] * (pd * pd + td * td);
    }

    acc = wave_reduce(acc);
    if (lane == 0) sred[wv] = acc;
    __syncthreads();
    if (y == 0) {
        float blocksum = sred[0] + sred[1] + sred[2] + sred[3];
        unsafeAtomicAdd(out, blocksum * (1.0f / (float)TOTAL));
    }
}

extern "C" void kernel_launch(void* const* d_in, const int* in_sizes, int n_in,
                              void* d_out, int out_size, void* d_ws, size_t ws_size,
                              hipStream_t stream) {
    const float* pred  = (const float*)d_in[0];
    const int* target  = (const int*)d_in[1];
    float* out = (float*)d_out;

    float* ws = (float*)d_ws;
    ushort4* dbuf_t = (ushort4*)ws;                 // 16*65536*8 B (8 MB)
    float*   peT    = ws + 2097152;                 // 1,048,576 floats (4 MB)

    fused_rows<<<NB * HH, 256, 0, stream>>>(pred, target, dbuf_t, peT, out);
    dt_cols_loss<<<NIMG * WW / 4, 256, 0, stream>>>(dbuf_t, peT, out);
}

// Round 7
// 34.411 us; speedup vs baseline: 1.4180x; 1.4180x over previous
//
#include <hip/hip_runtime.h>

#define HH 256
#define WW 256
#define NB 4
#define NC 4
#define NPIX (HH*WW)            // 65536
#define NIMG (NB*NC)            // 16
#define TOTAL (NB*NC*HH*WW)     // 1048576
#define INF_G (1<<30)

__device__ __forceinline__ float wave_reduce(float v) {
    #pragma unroll
    for (int off = 32; off > 0; off >>= 1) v += __shfl_down(v, off);
    return v;
}

// distance from x to nearest set bit in a 256-bit mask (4 u64 words); INT_MAX if none
__device__ __forceinline__ int nearest_dist(const unsigned long long* m, int x) {
    int best = 0x7fffffff;
    #pragma unroll
    for (int w = 0; w < 4; ++w) {
        unsigned long long mm = m[w];
        if (!mm) continue;
        int rel = x - (w << 6);
        // left side: highest set bit at position <= rel
        unsigned long long lmask = (rel >= 63) ? ~0ull
                                 : ((rel < 0) ? 0ull : ((2ull << (rel & 63)) - 1ull));
        unsigned long long lm = mm & lmask;
        if (lm) best = min(best, rel - (63 - __clzll(lm)));
        // right side: lowest set bit at position >= rel
        unsigned long long rmask = (rel <= 0) ? ~0ull
                                 : ((rel > 63) ? 0ull : (~0ull << (rel & 63)));
        unsigned long long rm = mm & rmask;
        if (rm) best = min(best, (__ffsll((long long)rm) - 1) - rel);
    }
    return best;
}

// Fused softmax + row-DT. block = (b, y); thread = x.
// Per pixel, per source (P/T) only ONE nearest-site search is needed: the search
// against the OPPOSITE set of the pixel's own class (the same-set distance is
// exactly 0). Code per source: bit8 = fg, bit9 = searched-set-row-empty, low 8 = d.
// Packed write (transposed for coalesced column reads):
//   buf[img][x][y] = uint2{ codeP | codeT<<16, bits(pe) }
__global__ void fused_rows(const float* __restrict__ pred, const int* __restrict__ target,
                           uint2* __restrict__ buf) {
    int blk = blockIdx.x;           // b*256 + y
    int b = blk >> 8, y = blk & 255;
    int x = threadIdx.x;

    const float* base = pred + (((size_t)b * NC) * HH + y) * WW + x;
    float v0 = base[0 * (size_t)NPIX];
    float v1 = base[1 * (size_t)NPIX];
    float v2 = base[2 * (size_t)NPIX];
    float v3 = base[3 * (size_t)NPIX];
    float m = fmaxf(fmaxf(v0, v1), fmaxf(v2, v3));
    float e0 = expf(v0 - m), e1 = expf(v1 - m), e2 = expf(v2 - m), e3 = expf(v3 - m);
    float inv = 1.0f / (e0 + e1 + e2 + e3);
    float p[4] = { e0 * inv, e1 * inv, e2 * inv, e3 * inv };

    int tc = target[((size_t)b * HH + y) * WW + x];

    __shared__ unsigned long long mP[4][4], mT[4][4];   // [class][word]
    int lane = x & 63, wave = x >> 6;
    #pragma unroll
    for (int c = 0; c < 4; ++c) {
        unsigned long long bp = __ballot(p[c] > 0.5f);
        unsigned long long bt = __ballot(tc == c);
        if (lane == 0) { mP[c][wave] = bp; mT[c][wave] = bt; }
    }
    __syncthreads();

    #pragma unroll
    for (int c = 0; c < 4; ++c) {
        bool fgP = p[c] > 0.5f;
        bool fgT = (tc == c);
        unsigned long long flipP = fgP ? ~0ull : 0ull;   // fg -> search complement (~fg sites)
        unsigned long long flipT = fgT ? ~0ull : 0ull;
        unsigned long long selP[4], selT[4];
        #pragma unroll
        for (int w = 0; w < 4; ++w) {
            selP[w] = mP[c][w] ^ flipP;
            selT[w] = mT[c][w] ^ flipT;
        }
        int dP = nearest_dist(selP, x);
        int dT = nearest_dist(selT, x);

        unsigned int codeP = (fgP ? 0x100u : 0u) | ((dP > 255) ? 0x200u : (unsigned int)dP);
        unsigned int codeT = (fgT ? 0x100u : 0u) | ((dT > 255) ? 0x200u : (unsigned int)dT);

        float t = fgT ? 1.0f : 0.0f;
        float d = p[c] - t;
        float pe = d * d;

        size_t ti = (((size_t)(b * NC + c)) * WW + x) * HH + y;   // transposed
        uint2 outv;
        outv.x = codeP | (codeT << 16);
        outv.y = __float_as_uint(pe);
        buf[ti] = outv;
    }
}

// Column pass + loss. block = (img, x), thread = y. Coalesced 8B loads.
// g[0/1] = P fg-dist/bg-dist squared row distances; g[2/3] same for T.
// Each thread searches only its selected variant per source (other is exactly 0).
__global__ void dt_cols_loss(const uint2* __restrict__ buf, float* __restrict__ partials) {
    int blk = blockIdx.x;
    int img = blk >> 8, x = blk & 255;
    int y = threadIdx.x;
    int lane = y & 63, wv = y >> 6;

    size_t ti = (((size_t)img) * WW + x) * HH + y;

    __shared__ int g[4][HH];
    __shared__ int sF[8];
    __shared__ float sred[4];

    uint2 v = buf[ti];
    unsigned int cP = v.x & 0xFFFFu, cT = v.x >> 16;
    int fgP = (cP >> 8) & 1, emP = (cP >> 9) & 1, dP = (int)(cP & 0xFFu);
    int fgT = (cT >> 8) & 1, emT = (cT >> 9) & 1, dT = (int)(cT & 0xFFu);
    int vP = emP ? INF_G : dP * dP;
    int vT = emT ? INF_G : dT * dT;
    g[0][y] = fgP ? vP : 0;     // sites = ~fgP  (fg_dist)
    g[1][y] = fgP ? 0 : vP;     // sites =  fgP  (bg_dist)
    g[2][y] = fgT ? vT : 0;
    g[3][y] = fgT ? 0 : vT;

    // row-has-fg is x-independent: fg pixel -> row has fg; bg pixel -> !empty(fg search)
    unsigned long long bP = __ballot(fgP || !emP);
    unsigned long long bT = __ballot(fgT || !emT);
    if (lane == 0) { sF[wv] = (bP != 0ull); sF[4 + wv] = (bT != 0ull); }
    __syncthreads();

    int hs1 = sF[0] | sF[1] | sF[2] | sF[3];   // any(fgP) in image
    int hs3 = sF[4] | sF[5] | sF[6] | sF[7];   // any(fgT) in image

    const int* gP = fgP ? g[0] : g[1];
    const int* gT = fgT ? g[2] : g[3];

    float dtP, dtT;
    {
        int best = gP[y];
        for (int s = 1; s < HH; ++s) {
            int ss = s * s;
            if (ss >= best) break;
            int jm = y - s;
            if (jm >= 0) best = min(best, gP[jm] + ss);
            int jp = y + s;
            if (jp < HH) best = min(best, gP[jp] + ss);
        }
        dtP = (best >= INF_G) ? sqrtf(1.0e9f) : sqrtf((float)best);
    }
    {
        int best = gT[y];
        for (int s = 1; s < HH; ++s) {
            int ss = s * s;
            if (ss >= best) break;
            int jm = y - s;
            if (jm >= 0) best = min(best, gT[jm] + ss);
            int jp = y + s;
            if (jp < HH) best = min(best, gT[jp] + ss);
        }
        dtT = (best >= INF_G) ? sqrtf(1.0e9f) : sqrtf((float)best);
    }

    float pe = __uint_as_float(v.y);
    float pd = hs1 ? dtP : 0.0f;    // other pair member is exactly 0
    float td = hs3 ? dtT : 0.0f;
    float val = pe * (pd * pd + td * td);

    val = wave_reduce(val);
    if (lane == 0) sred[wv] = val;
    __syncthreads();
    if (y == 0)
        partials[blk] = sred[0] + sred[1] + sred[2] + sred[3];
}

__global__ void final_kernel(const float* __restrict__ partials, float* __restrict__ out) {
    float a = 0.0f;
    for (int i = threadIdx.x; i < 4096; i += 256) a += partials[i];
    a = wave_reduce(a);
    __shared__ float s[4];
    int lane = threadIdx.x & 63, wave = threadIdx.x >> 6;
    if (lane == 0) s[wave] = a;
    __syncthreads();
    if (threadIdx.x == 0)
        out[0] = (s[0] + s[1] + s[2] + s[3]) * (1.0f / (float)TOTAL);
}

extern "C" void kernel_launch(void* const* d_in, const int* in_sizes, int n_in,
                              void* d_out, int out_size, void* d_ws, size_t ws_size,
                              hipStream_t stream) {
    const float* pred  = (const float*)d_in[0];
    const int* target  = (const int*)d_in[1];
    float* out = (float*)d_out;

    float* ws = (float*)d_ws;
    uint2* buf      = (uint2*)ws;                   // 16*65536*8 B (8 MB)
    float* partials = ws + 2097152;                 // 4096 floats

    fused_rows<<<NB * HH, 256, 0, stream>>>(pred, target, buf);
    dt_cols_loss<<<NIMG * WW, 256, 0, stream>>>(buf, partials);
    final_kernel<<<1, 256, 0, stream>>>(partials, out);
}